// Round 17
// baseline (154.855 us; speedup 1.0000x reference)
//
#include <hip/hip_runtime.h>
#include <math.h>

#define BB 4
#define TT 2048
#define CC 768
#define HH 12
#define DD 64
#define RS (3 * CC)

typedef __bf16 bf16x8 __attribute__((ext_vector_type(8)));
typedef float f32x4 __attribute__((ext_vector_type(4)));
typedef unsigned short u16x8 __attribute__((ext_vector_type(8)));
typedef unsigned short u16x4 __attribute__((ext_vector_type(4)));

union U8 { bf16x8 v; u16x8 s; unsigned short u[8]; };
union BCV { __bf16 h; unsigned short u; };

__device__ __forceinline__ unsigned short f2bf(float f) {
  union { float f; unsigned u; } x; x.f = f;
  unsigned r = x.u + 0x7fffu + ((x.u >> 16) & 1u);
  return (unsigned short)(r >> 16);
}
__device__ __forceinline__ float bf2f(unsigned short u) {
  union { unsigned u; float f; } x; x.u = (unsigned)u << 16;
  return x.f;
}

#define AS1 __attribute__((address_space(1)))
#define AS3 __attribute__((address_space(3)))
__device__ __forceinline__ void gl_lds16(const void* g, void* l) {
  __builtin_amdgcn_global_load_lds((const AS1 unsigned int*)g,
                                   (AS3 unsigned int*)l, 16, 0, 0);
}

// XCD-chunked block swizzle (T1, kept: R15 FETCH 70.7->47.7 MB on GEMM1)
__device__ __forceinline__ void xcd_swizzle(int gx, int& bx, int& by) {
  const int nwg = gx * gridDim.y;
  const int hid = blockIdx.y * gx + blockIdx.x;
  const int id2 = (hid % 8) * (nwg / 8) + hid / 8;
  by = id2 / gx;
  bx = id2 % gx;
}

// ---------------------------------------------------------------------------
// prep: fp32 -> bf16 elementwise (x -> xb)
// ---------------------------------------------------------------------------
__global__ __launch_bounds__(256) void cvt_bf16_kernel(
    const float* __restrict__ in, unsigned short* __restrict__ out, int n8) {
  int i = blockIdx.x * 256 + threadIdx.x;
  const int stride = gridDim.x * 256;
  for (; i < n8; i += stride) {
    const float4 a = reinterpret_cast<const float4*>(in)[i * 2];
    const float4 b = reinterpret_cast<const float4*>(in)[i * 2 + 1];
    U8 p;
    p.u[0] = f2bf(a.x); p.u[1] = f2bf(a.y); p.u[2] = f2bf(a.z); p.u[3] = f2bf(a.w);
    p.u[4] = f2bf(b.x); p.u[5] = f2bf(b.y); p.u[6] = f2bf(b.z); p.u[7] = f2bf(b.w);
    reinterpret_cast<u16x8*>(out)[i] = p.s;
  }
}

// ---------------------------------------------------------------------------
// prep: W[K][N] fp32 -> Wt[N][K] bf16 (64x64 LDS tile transpose)
// ---------------------------------------------------------------------------
__global__ __launch_bounds__(256) void transpose_cvt_kernel(
    const float* __restrict__ in, unsigned short* __restrict__ out,
    int K, int N) {
  __shared__ float T[64][65];
  const int k0 = blockIdx.y * 64, n0 = blockIdx.x * 64;
  const int tid = threadIdx.x;
  const int ty = tid >> 4, tx4 = (tid & 15) * 4;
#pragma unroll
  for (int i = 0; i < 4; ++i) {
    const int r = ty + i * 16;
    const float4 v = *reinterpret_cast<const float4*>(
        &in[(size_t)(k0 + r) * N + n0 + tx4]);
    T[r][tx4] = v.x; T[r][tx4 + 1] = v.y; T[r][tx4 + 2] = v.z; T[r][tx4 + 3] = v.w;
  }
  __syncthreads();
  const int nrow = tid >> 2, kc = (tid & 3) * 16;
  U8 p0, p1;
#pragma unroll
  for (int i = 0; i < 8; ++i) {
    p0.u[i] = f2bf(T[kc + i][nrow]);
    p1.u[i] = f2bf(T[kc + 8 + i][nrow]);
  }
  unsigned short* o = &out[(size_t)(n0 + nrow) * K + k0 + kc];
  *reinterpret_cast<u16x8*>(o) = p0.s;
  *reinterpret_cast<u16x8*>(o + 8) = p1.s;
}

// ---------------------------------------------------------------------------
// GEMM core loop macro helpers (counted-vmcnt 2-barrier pipeline, T4):
//   iter t: issue(t+1) -> s_waitcnt vmcnt(4) -> s_barrier -> MFMA(t) -> s_barrier
// Tile t's loads get a full iteration to land; barriers never drain prefetch.
// ---------------------------------------------------------------------------
#define GEMM_STAGE(buf)                                        \
  gl_lds16(gA + kn, As[buf] + w * 512);                        \
  gl_lds16(gA + (size_t)64 * K + kn, As[buf] + w * 512 + 2048);\
  gl_lds16(gB + kn, Bs[buf] + w * 512);                        \
  gl_lds16(gB + (size_t)64 * K + kn, Bs[buf] + w * 512 + 2048);

#define GEMM_COMPUTE(buf)                                                     \
  {                                                                           \
    bf16x8 af[4], bf[4];                                                      \
    _Pragma("unroll") for (int mf = 0; mf < 4; ++mf)                          \
        af[mf] = *reinterpret_cast<const bf16x8*>(                            \
            &As[buf][(wr * 64 + mf * 16 + lr) * 32 + eb]);                    \
    _Pragma("unroll") for (int nf = 0; nf < 4; ++nf)                          \
        bf[nf] = *reinterpret_cast<const bf16x8*>(                            \
            &Bs[buf][(wc * 64 + nf * 16 + lr) * 32 + eb]);                    \
    _Pragma("unroll") for (int mf = 0; mf < 4; ++mf)                          \
        _Pragma("unroll") for (int nf = 0; nf < 4; ++nf)                      \
            acc[mf][nf] = __builtin_amdgcn_mfma_f32_16x16x32_bf16(            \
                af[mf], bf[nf], acc[mf][nf], 0, 0, 0);                        \
  }

// ---------------------------------------------------------------------------
// bf16 MFMA GEMM1 (counted-vmcnt pipeline), fused V^T epilogue
// ---------------------------------------------------------------------------
__global__ __launch_bounds__(256) void gemm1_kernel(
    const unsigned short* __restrict__ A, const unsigned short* __restrict__ Bt,
    const float* __restrict__ bias, unsigned short* __restrict__ Cq,
    unsigned short* __restrict__ Vg, int M, int N, int K) {
  __shared__ unsigned short As[2][128 * 32];
  __shared__ unsigned short Bs[2][128 * 32];

  int bx, by;
  xcd_swizzle(gridDim.x, bx, by);
  const int tid = threadIdx.x;
  const int w = tid >> 6, l = tid & 63, lr = l & 15, lg = l >> 4;
  const int wr = w >> 1, wc = w & 1;
  const int brow = by * 128, bcol = bx * 128;

  f32x4 acc[4][4];
#pragma unroll
  for (int i = 0; i < 4; ++i)
#pragma unroll
    for (int j = 0; j < 4; ++j) acc[i][j] = (f32x4)(0.f);

  const int r0 = tid >> 2;
  const int c8 = (((tid & 3) ^ (r0 & 3))) * 8;
  const unsigned short* gA = A + (size_t)(brow + r0) * K + c8;
  const unsigned short* gB = Bt + (size_t)(bcol + r0) * K + c8;
  const int eb = (lg ^ (lr & 3)) * 8;

  const int nt = K / 32;
  { const int kn = 0; GEMM_STAGE(0) }   // prologue: tile 0

  int cur = 0;
  for (int t = 0; t < nt - 1; ++t) {    // main: next tile always exists
    const int kn = (t + 1) * 32;
    GEMM_STAGE(cur ^ 1)
    asm volatile("s_waitcnt vmcnt(4)" ::: "memory");  // tile t's loads done
    asm volatile("s_barrier" ::: "memory");
    GEMM_COMPUTE(cur)
    asm volatile("s_barrier" ::: "memory");           // all done reading buf[cur]
    cur ^= 1;
  }
  // epilogue iteration: no prefetch
  asm volatile("s_waitcnt vmcnt(0)" ::: "memory");
  asm volatile("s_barrier" ::: "memory");
  GEMM_COMPUTE(cur)

  if (bcol >= 2 * CC) {
    const int bloc = brow >> 11;
    const int tokw = (brow & 2047) + wr * 64;
#pragma unroll
    for (int nf = 0; nf < 4; ++nf) {
      const int hd = bcol - 2 * CC + wc * 64 + nf * 16 + lr;
      const float bv = bias[bcol + wc * 64 + nf * 16 + lr];
      unsigned short* vdst =
          Vg + ((size_t)(bloc * HH + (hd >> 6)) * DD + (hd & 63)) * TT + tokw;
#pragma unroll
      for (int mf = 0; mf < 4; ++mf) {
        u16x4 pk;
#pragma unroll
        for (int r = 0; r < 4; ++r) pk[r] = f2bf(acc[mf][nf][r] + bv);
        *reinterpret_cast<u16x4*>(vdst + mf * 16 + lg * 4) = pk;
      }
    }
  } else {
#pragma unroll
    for (int nf = 0; nf < 4; ++nf) {
      const int col = bcol + wc * 64 + nf * 16 + lr;
      const float bv = bias[col];
#pragma unroll
      for (int mf = 0; mf < 4; ++mf) {
        const int row0 = brow + wr * 64 + mf * 16 + lg * 4;
#pragma unroll
        for (int r = 0; r < 4; ++r)
          Cq[(size_t)(row0 + r) * N + col] = f2bf(acc[mf][nf][r] + bv);
      }
    }
  }
}

// ---------------------------------------------------------------------------
// bf16 MFMA GEMM2 (counted-vmcnt pipeline, fp32 out)
// ---------------------------------------------------------------------------
__global__ __launch_bounds__(256) void gemm2_kernel(
    const unsigned short* __restrict__ A, const unsigned short* __restrict__ Bt,
    const float* __restrict__ bias, float* __restrict__ C,
    int M, int N, int K) {
  __shared__ unsigned short As[2][128 * 32];
  __shared__ unsigned short Bs[2][128 * 32];

  int bx, by;
  xcd_swizzle(gridDim.x, bx, by);
  const int tid = threadIdx.x;
  const int w = tid >> 6, l = tid & 63, lr = l & 15, lg = l >> 4;
  const int wr = w >> 1, wc = w & 1;
  const int brow = by * 128, bcol = bx * 128;

  f32x4 acc[4][4];
#pragma unroll
  for (int i = 0; i < 4; ++i)
#pragma unroll
    for (int j = 0; j < 4; ++j) acc[i][j] = (f32x4)(0.f);

  const int r0 = tid >> 2;
  const int c8 = (((tid & 3) ^ (r0 & 3))) * 8;
  const unsigned short* gA = A + (size_t)(brow + r0) * K + c8;
  const unsigned short* gB = Bt + (size_t)(bcol + r0) * K + c8;
  const int eb = (lg ^ (lr & 3)) * 8;

  const int nt = K / 32;
  { const int kn = 0; GEMM_STAGE(0) }

  int cur = 0;
  for (int t = 0; t < nt - 1; ++t) {
    const int kn = (t + 1) * 32;
    GEMM_STAGE(cur ^ 1)
    asm volatile("s_waitcnt vmcnt(4)" ::: "memory");
    asm volatile("s_barrier" ::: "memory");
    GEMM_COMPUTE(cur)
    asm volatile("s_barrier" ::: "memory");
    cur ^= 1;
  }
  asm volatile("s_waitcnt vmcnt(0)" ::: "memory");
  asm volatile("s_barrier" ::: "memory");
  GEMM_COMPUTE(cur)

#pragma unroll
  for (int nf = 0; nf < 4; ++nf) {
    const int col = bcol + wc * 64 + nf * 16 + lr;
    const float bv = bias[col];
#pragma unroll
    for (int mf = 0; mf < 4; ++mf) {
      const int row0 = brow + wr * 64 + mf * 16 + lg * 4;
#pragma unroll
      for (int r = 0; r < 4; ++r)
        C[(size_t)(row0 + r) * N + col] = acc[mf][nf][r] + bv;
    }
  }
}

// ---------------------------------------------------------------------------
// bf16 MFMA flash attention — REVERTED to the R13-proven 256-thread kernel
// (64.4 us measured; R16 paired-512 variant was 66.4). Static-max softmax,
// swizzled [64][64] LDS (0 conflicts), setprio, masked-skip, qscale folded
// into Q load, single q-group per block, longest-first dispatch.
// ---------------------------------------------------------------------------
constexpr int KVT = 64;

__global__ __launch_bounds__(256) void attn_mfma_kernel(
    const unsigned short* __restrict__ qkv,
    const unsigned short* __restrict__ Vg,   // [48][64][2048]
    unsigned short* __restrict__ y) {
  __shared__ unsigned short Ks[KVT * 64];    // 8KB, swizzled
  __shared__ unsigned short Vt[DD * 64];     // 8KB, swizzled
  __shared__ unsigned short Pl[4 * 16 * 64]; // 8KB, per-wave, swizzled

  const int tid = threadIdx.x;
  const int w = tid >> 6, l = tid & 63;
  const int lr = l & 15, lg = l >> 4;
  const int bh = blockIdx.x, b = bh / HH, h = bh % HH;
  const int g = 31 - blockIdx.y;           // longest-first
  const int qw = g * 64 + w * 16;

  const unsigned short* qbase = qkv + (size_t)b * TT * RS + h * DD;
  const unsigned short* kbase = qkv + (size_t)b * TT * RS + (HH + h) * DD;
  const unsigned short* vgb = Vg + (size_t)bh * DD * TT;

  const float qscale = 0.125f * 1.44269504f;
  const int e = lg ^ (lr & 7);
  const int e4 = e ^ 4;

  bf16x8 qf[2];
  {
    const unsigned short* qrow = qbase + (size_t)(qw + lr) * RS;
#pragma unroll
    for (int hf = 0; hf < 2; ++hf) {
      const u16x8 raw = *reinterpret_cast<const u16x8*>(qrow + lg * 8 + hf * 32);
      U8 t;
#pragma unroll
      for (int i = 0; i < 8; ++i) t.u[i] = f2bf(bf2f(raw[i]) * qscale);
      qf[hf] = t.v;
    }
  }

  f32x4 O[4];
  f32x4 ls = (f32x4)(0.f);
#pragma unroll
  for (int nb = 0; nb < 4; ++nb) O[nb] = (f32x4)(0.f);

  const int srow = tid >> 2, sc2 = (tid & 3) * 2;
  const int sw = srow & 7;
  const int sidx0 = srow * 64 + 8 * (sc2 ^ sw);
  const int sidx1 = srow * 64 + 8 * ((sc2 + 1) ^ sw);
  const int scol = (tid & 3) * 16;
  const unsigned short* kptr = kbase + (size_t)srow * RS + scol;
  const unsigned short* vptr = vgb + (size_t)srow * TT + scol;

  const int ntiles = g + 1;
  u16x8 kr0 = *reinterpret_cast<const u16x8*>(kptr);
  u16x8 kr1 = *reinterpret_cast<const u16x8*>(kptr + 8);
  u16x8 vr0 = *reinterpret_cast<const u16x8*>(vptr);
  u16x8 vr1 = *reinterpret_cast<const u16x8*>(vptr + 8);

  for (int t = 0; t < ntiles; ++t) {
    const int kv0 = t * KVT;
    __syncthreads();
    *reinterpret_cast<u16x8*>(&Ks[sidx0]) = kr0;
    *reinterpret_cast<u16x8*>(&Ks[sidx1]) = kr1;
    *reinterpret_cast<u16x8*>(&Vt[sidx0]) = vr0;
    *reinterpret_cast<u16x8*>(&Vt[sidx1]) = vr1;
    if (t + 1 < ntiles) {
      kptr += (size_t)KVT * RS;
      vptr += KVT;
      kr0 = *reinterpret_cast<const u16x8*>(kptr);
      kr1 = *reinterpret_cast<const u16x8*>(kptr + 8);
      vr0 = *reinterpret_cast<const u16x8*>(vptr);
      vr1 = *reinterpret_cast<const u16x8*>(vptr + 8);
    }
    __syncthreads();

    const bool diag = (t == g);
    const int nbmax = diag ? (w + 1) : 4;

    f32x4 s[4];
#pragma unroll
    for (int nb = 0; nb < 4; ++nb) s[nb] = (f32x4)(0.f);
    __builtin_amdgcn_s_setprio(1);
#pragma unroll
    for (int nb = 0; nb < 4; ++nb) {
      if (nb >= nbmax) continue;
      const int krow = (nb * 16 + lr) * 64;
      const bf16x8 k0 = *reinterpret_cast<const bf16x8*>(&Ks[krow + 8 * e]);
      const bf16x8 k1 = *reinterpret_cast<const bf16x8*>(&Ks[krow + 8 * e4]);
      s[nb] = __builtin_amdgcn_mfma_f32_16x16x32_bf16(qf[0], k0, s[nb], 0, 0, 0);
      s[nb] = __builtin_amdgcn_mfma_f32_16x16x32_bf16(qf[1], k1, s[nb], 0, 0, 0);
    }
    __builtin_amdgcn_s_setprio(0);

    if (diag) {
      const int qrow = qw + lg * 4;
#pragma unroll
      for (int nb = 0; nb < 4; ++nb) {
        if (nb >= nbmax) continue;
        const int key = kv0 + nb * 16 + lr;
#pragma unroll
        for (int r = 0; r < 4; ++r)
          if (key > qrow + r) s[nb][r] = -1e30f;
      }
    }
#pragma unroll
    for (int r = 0; r < 4; ++r) {
      const int prow = lg * 4 + r;
      const int pswz = (prow & 7) << 3;
      unsigned short* pbase = &Pl[w * 1024 + prow * 64];
#pragma unroll
      for (int nb = 0; nb < 4; ++nb) {
        if (nb >= nbmax) {
          pbase[(nb * 16 + lr) ^ pswz] = 0;
          continue;
        }
        const float p = exp2f(s[nb][r]);
        ls[r] += p;
        BCV cv; cv.h = (__bf16)p;
        pbase[(nb * 16 + lr) ^ pswz] = cv.u;
      }
    }

    asm volatile("s_waitcnt lgkmcnt(0)" ::: "memory");

    {
      const unsigned short* pw = &Pl[w * 1024];
      const bf16x8 pa0 = *reinterpret_cast<const bf16x8*>(&pw[lr * 64 + 8 * e]);
      const bf16x8 pa1 = *reinterpret_cast<const bf16x8*>(&pw[lr * 64 + 8 * e4]);
      __builtin_amdgcn_s_setprio(1);
#pragma unroll
      for (int nb = 0; nb < 4; ++nb) {
        const int vrow = (nb * 16 + lr) * 64;
        const bf16x8 v0 = *reinterpret_cast<const bf16x8*>(&Vt[vrow + 8 * e]);
        const bf16x8 v1 = *reinterpret_cast<const bf16x8*>(&Vt[vrow + 8 * e4]);
        O[nb] = __builtin_amdgcn_mfma_f32_16x16x32_bf16(pa0, v0, O[nb], 0, 0, 0);
        O[nb] = __builtin_amdgcn_mfma_f32_16x16x32_bf16(pa1, v1, O[nb], 0, 0, 0);
      }
      __builtin_amdgcn_s_setprio(0);
    }
  }

#pragma unroll
  for (int off = 1; off < 16; off <<= 1)
#pragma unroll
    for (int r = 0; r < 4; ++r) ls[r] += __shfl_xor(ls[r], off, 64);
  f32x4 inv;
#pragma unroll
  for (int r = 0; r < 4; ++r) inv[r] = 1.f / ls[r];
#pragma unroll
  for (int nb = 0; nb < 4; ++nb)
#pragma unroll
    for (int r = 0; r < 4; ++r)
      y[((size_t)b * TT + qw + lg * 4 + r) * CC + h * DD + nb * 16 + lr] =
          f2bf(O[nb][r] * inv[r]);
}

extern "C" void kernel_launch(void* const* d_in, const int* in_sizes, int n_in,
                              void* d_out, int out_size, void* d_ws, size_t ws_size,
                              hipStream_t stream) {
  const float* x      = (const float*)d_in[0];
  const float* W_attn = (const float*)d_in[2];
  const float* b_attn = (const float*)d_in[3];
  const float* W_proj = (const float*)d_in[4];
  const float* b_proj = (const float*)d_in[5];
  float* out = (float*)d_out;

  const int M = BB * TT;  // 8192
  unsigned short* qkvb = (unsigned short*)d_ws;            // [8192][2304]
  unsigned short* xb   = qkvb + (size_t)M * RS;            // [8192][768]
  unsigned short* yb   = xb + (size_t)M * CC;              // [8192][768]
  unsigned short* Wt1  = yb + (size_t)M * CC;              // [2304][768]
  unsigned short* Wt2  = Wt1 + (size_t)RS * CC;            // [768][768]
  unsigned short* Vg   = Wt2 + (size_t)CC * CC;            // [48][64][2048]

  cvt_bf16_kernel<<<1024, 256, 0, stream>>>(x, xb, M * CC / 8);
  transpose_cvt_kernel<<<dim3(RS / 64, CC / 64), 256, 0, stream>>>(
      W_attn, Wt1, CC, RS);
  transpose_cvt_kernel<<<dim3(CC / 64, CC / 64), 256, 0, stream>>>(
      W_proj, Wt2, CC, CC);

  gemm1_kernel<<<dim3(RS / 128, M / 128), 256, 0, stream>>>(
      xb, Wt1, b_attn, qkvb, Vg, M, RS, CC);

  attn_mfma_kernel<<<dim3(BB * HH, 32), 256, 0, stream>>>(qkvb, Vg, yb);

  gemm2_kernel<<<dim3(CC / 128, M / 128), 256, 0, stream>>>(
      yb, Wt2, b_proj, out, M, CC, CC);
}

// Round 20
// 149.150 us; speedup vs baseline: 1.0383x; 1.0383x over previous
//
#include <hip/hip_runtime.h>
#include <math.h>

#define BB 4
#define TT 2048
#define CC 768
#define HH 12
#define DD 64
#define RS (3 * CC)

typedef __bf16 bf16x8 __attribute__((ext_vector_type(8)));
typedef float f32x4 __attribute__((ext_vector_type(4)));
typedef unsigned short u16x8 __attribute__((ext_vector_type(8)));
typedef unsigned short u16x4 __attribute__((ext_vector_type(4)));

union U8 { bf16x8 v; u16x8 s; unsigned short u[8]; };
union BCV { __bf16 h; unsigned short u; };

__device__ __forceinline__ unsigned short f2bf(float f) {
  union { float f; unsigned u; } x; x.f = f;
  unsigned r = x.u + 0x7fffu + ((x.u >> 16) & 1u);
  return (unsigned short)(r >> 16);
}
__device__ __forceinline__ float bf2f(unsigned short u) {
  union { unsigned u; float f; } x; x.u = (unsigned)u << 16;
  return x.f;
}

#define AS1 __attribute__((address_space(1)))
#define AS3 __attribute__((address_space(3)))
__device__ __forceinline__ void gl_lds16(const void* g, void* l) {
  __builtin_amdgcn_global_load_lds((const AS1 unsigned int*)g,
                                   (AS3 unsigned int*)l, 16, 0, 0);
}

// XCD-chunked block swizzle (T1; R15: GEMM1 FETCH 70.7->47.7 MB)
__device__ __forceinline__ void xcd_swizzle(int gx, int& bx, int& by) {
  const int nwg = gx * gridDim.y;
  const int hid = blockIdx.y * gx + blockIdx.x;
  const int id2 = (hid % 8) * (nwg / 8) + hid / 8;
  by = id2 / gx;
  bx = id2 % gx;
}

// ---------------------------------------------------------------------------
// prep: fp32 -> bf16 elementwise (x -> xb)
// ---------------------------------------------------------------------------
__global__ __launch_bounds__(256) void cvt_bf16_kernel(
    const float* __restrict__ in, unsigned short* __restrict__ out, int n8) {
  int i = blockIdx.x * 256 + threadIdx.x;
  const int stride = gridDim.x * 256;
  for (; i < n8; i += stride) {
    const float4 a = reinterpret_cast<const float4*>(in)[i * 2];
    const float4 b = reinterpret_cast<const float4*>(in)[i * 2 + 1];
    U8 p;
    p.u[0] = f2bf(a.x); p.u[1] = f2bf(a.y); p.u[2] = f2bf(a.z); p.u[3] = f2bf(a.w);
    p.u[4] = f2bf(b.x); p.u[5] = f2bf(b.y); p.u[6] = f2bf(b.z); p.u[7] = f2bf(b.w);
    reinterpret_cast<u16x8*>(out)[i] = p.s;
  }
}

// ---------------------------------------------------------------------------
// prep: BOTH weight transposes in one launch. z=0: W_attn->Wt1 (N=RS);
// z=1: W_proj->Wt2 (N=CC). 64x64 LDS tile transpose, fp32->bf16.
// ---------------------------------------------------------------------------
__global__ __launch_bounds__(256) void transpose2_kernel(
    const float* __restrict__ Wa, unsigned short* __restrict__ Wt1,
    const float* __restrict__ Wp, unsigned short* __restrict__ Wt2) {
  const int z = blockIdx.z;
  if (z == 1 && blockIdx.x >= CC / 64) return;   // block-uniform early exit
  const float* in = z ? Wp : Wa;
  unsigned short* out = z ? Wt2 : Wt1;
  const int N = z ? CC : RS;
  const int K = CC;

  __shared__ float T[64][65];
  const int k0 = blockIdx.y * 64, n0 = blockIdx.x * 64;
  const int tid = threadIdx.x;
  const int ty = tid >> 4, tx4 = (tid & 15) * 4;
#pragma unroll
  for (int i = 0; i < 4; ++i) {
    const int r = ty + i * 16;
    const float4 v = *reinterpret_cast<const float4*>(
        &in[(size_t)(k0 + r) * N + n0 + tx4]);
    T[r][tx4] = v.x; T[r][tx4 + 1] = v.y; T[r][tx4 + 2] = v.z; T[r][tx4 + 3] = v.w;
  }
  __syncthreads();
  const int nrow = tid >> 2, kc = (tid & 3) * 16;
  U8 p0, p1;
#pragma unroll
  for (int i = 0; i < 8; ++i) {
    p0.u[i] = f2bf(T[kc + i][nrow]);
    p1.u[i] = f2bf(T[kc + 8 + i][nrow]);
  }
  unsigned short* o = &out[(size_t)(n0 + nrow) * K + k0 + kc];
  *reinterpret_cast<u16x8*>(o) = p0.s;
  *reinterpret_cast<u16x8*>(o + 8) = p1.s;
}

// ---------------------------------------------------------------------------
// bf16 MFMA GEMM1 (R15-proven dbuf structure), fused V^T epilogue
// ---------------------------------------------------------------------------
__global__ __launch_bounds__(256) void gemm1_kernel(
    const unsigned short* __restrict__ A, const unsigned short* __restrict__ Bt,
    const float* __restrict__ bias, unsigned short* __restrict__ Cq,
    unsigned short* __restrict__ Vg, int M, int N, int K) {
  __shared__ unsigned short As[2][128 * 32];
  __shared__ unsigned short Bs[2][128 * 32];

  int bx, by;
  xcd_swizzle(gridDim.x, bx, by);
  const int tid = threadIdx.x;
  const int w = tid >> 6, l = tid & 63, lr = l & 15, lg = l >> 4;
  const int wr = w >> 1, wc = w & 1;
  const int brow = by * 128, bcol = bx * 128;

  f32x4 acc[4][4];
#pragma unroll
  for (int i = 0; i < 4; ++i)
#pragma unroll
    for (int j = 0; j < 4; ++j) acc[i][j] = (f32x4)(0.f);

  const int r0 = tid >> 2;
  const int c8 = (((tid & 3) ^ (r0 & 3))) * 8;
  const unsigned short* gA = A + (size_t)(brow + r0) * K + c8;
  const unsigned short* gB = Bt + (size_t)(bcol + r0) * K + c8;
  const int eb = (lg ^ (lr & 3)) * 8;

  gl_lds16(gA, As[0] + w * 512);
  gl_lds16(gA + (size_t)64 * K, As[0] + w * 512 + 2048);
  gl_lds16(gB, Bs[0] + w * 512);
  gl_lds16(gB + (size_t)64 * K, Bs[0] + w * 512 + 2048);
  __syncthreads();

  int cur = 0;
  for (int k0 = 0; k0 < K; k0 += 32) {
    if (k0 + 32 < K) {
      const int kn = k0 + 32;
      gl_lds16(gA + kn, As[cur ^ 1] + w * 512);
      gl_lds16(gA + (size_t)64 * K + kn, As[cur ^ 1] + w * 512 + 2048);
      gl_lds16(gB + kn, Bs[cur ^ 1] + w * 512);
      gl_lds16(gB + (size_t)64 * K + kn, Bs[cur ^ 1] + w * 512 + 2048);
    }

    bf16x8 af[4], bf[4];
#pragma unroll
    for (int mf = 0; mf < 4; ++mf)
      af[mf] = *reinterpret_cast<const bf16x8*>(
          &As[cur][(wr * 64 + mf * 16 + lr) * 32 + eb]);
#pragma unroll
    for (int nf = 0; nf < 4; ++nf)
      bf[nf] = *reinterpret_cast<const bf16x8*>(
          &Bs[cur][(wc * 64 + nf * 16 + lr) * 32 + eb]);
#pragma unroll
    for (int mf = 0; mf < 4; ++mf)
#pragma unroll
      for (int nf = 0; nf < 4; ++nf)
        acc[mf][nf] = __builtin_amdgcn_mfma_f32_16x16x32_bf16(
            af[mf], bf[nf], acc[mf][nf], 0, 0, 0);

    __syncthreads();
    cur ^= 1;
  }

  if (bcol >= 2 * CC) {
    const int bloc = brow >> 11;
    const int tokw = (brow & 2047) + wr * 64;
#pragma unroll
    for (int nf = 0; nf < 4; ++nf) {
      const int hd = bcol - 2 * CC + wc * 64 + nf * 16 + lr;
      const float bv = bias[bcol + wc * 64 + nf * 16 + lr];
      unsigned short* vdst =
          Vg + ((size_t)(bloc * HH + (hd >> 6)) * DD + (hd & 63)) * TT + tokw;
#pragma unroll
      for (int mf = 0; mf < 4; ++mf) {
        u16x4 pk;
#pragma unroll
        for (int r = 0; r < 4; ++r) pk[r] = f2bf(acc[mf][nf][r] + bv);
        *reinterpret_cast<u16x4*>(vdst + mf * 16 + lg * 4) = pk;
      }
    }
  } else {
#pragma unroll
    for (int nf = 0; nf < 4; ++nf) {
      const int col = bcol + wc * 64 + nf * 16 + lr;
      const float bv = bias[col];
#pragma unroll
      for (int mf = 0; mf < 4; ++mf) {
        const int row0 = brow + wr * 64 + mf * 16 + lg * 4;
#pragma unroll
        for (int r = 0; r < 4; ++r)
          Cq[(size_t)(row0 + r) * N + col] = f2bf(acc[mf][nf][r] + bv);
      }
    }
  }
}

// ---------------------------------------------------------------------------
// bf16 MFMA GEMM2 (R15-proven dbuf structure, fp32 out)
// ---------------------------------------------------------------------------
__global__ __launch_bounds__(256) void gemm2_kernel(
    const unsigned short* __restrict__ A, const unsigned short* __restrict__ Bt,
    const float* __restrict__ bias, float* __restrict__ C,
    int M, int N, int K) {
  __shared__ unsigned short As[2][128 * 32];
  __shared__ unsigned short Bs[2][128 * 32];

  int bx, by;
  xcd_swizzle(gridDim.x, bx, by);
  const int tid = threadIdx.x;
  const int w = tid >> 6, l = tid & 63, lr = l & 15, lg = l >> 4;
  const int wr = w >> 1, wc = w & 1;
  const int brow = by * 128, bcol = bx * 128;

  f32x4 acc[4][4];
#pragma unroll
  for (int i = 0; i < 4; ++i)
#pragma unroll
    for (int j = 0; j < 4; ++j) acc[i][j] = (f32x4)(0.f);

  const int r0 = tid >> 2;
  const int c8 = (((tid & 3) ^ (r0 & 3))) * 8;
  const unsigned short* gA = A + (size_t)(brow + r0) * K + c8;
  const unsigned short* gB = Bt + (size_t)(bcol + r0) * K + c8;
  const int eb = (lg ^ (lr & 3)) * 8;

  gl_lds16(gA, As[0] + w * 512);
  gl_lds16(gA + (size_t)64 * K, As[0] + w * 512 + 2048);
  gl_lds16(gB, Bs[0] + w * 512);
  gl_lds16(gB + (size_t)64 * K, Bs[0] + w * 512 + 2048);
  __syncthreads();

  int cur = 0;
  for (int k0 = 0; k0 < K; k0 += 32) {
    if (k0 + 32 < K) {
      const int kn = k0 + 32;
      gl_lds16(gA + kn, As[cur ^ 1] + w * 512);
      gl_lds16(gA + (size_t)64 * K + kn, As[cur ^ 1] + w * 512 + 2048);
      gl_lds16(gB + kn, Bs[cur ^ 1] + w * 512);
      gl_lds16(gB + (size_t)64 * K + kn, Bs[cur ^ 1] + w * 512 + 2048);
    }

    bf16x8 af[4], bf[4];
#pragma unroll
    for (int mf = 0; mf < 4; ++mf)
      af[mf] = *reinterpret_cast<const bf16x8*>(
          &As[cur][(wr * 64 + mf * 16 + lr) * 32 + eb]);
#pragma unroll
    for (int nf = 0; nf < 4; ++nf)
      bf[nf] = *reinterpret_cast<const bf16x8*>(
          &Bs[cur][(wc * 64 + nf * 16 + lr) * 32 + eb]);
#pragma unroll
    for (int mf = 0; mf < 4; ++mf)
#pragma unroll
      for (int nf = 0; nf < 4; ++nf)
        acc[mf][nf] = __builtin_amdgcn_mfma_f32_16x16x32_bf16(
            af[mf], bf[nf], acc[mf][nf], 0, 0, 0);

    __syncthreads();
    cur ^= 1;
  }

#pragma unroll
  for (int nf = 0; nf < 4; ++nf) {
    const int col = bcol + wc * 64 + nf * 16 + lr;
    const float bv = bias[col];
#pragma unroll
    for (int mf = 0; mf < 4; ++mf) {
      const int row0 = brow + wr * 64 + mf * 16 + lg * 4;
#pragma unroll
      for (int r = 0; r < 4; ++r)
        C[(size_t)(row0 + r) * N + col] = acc[mf][nf][r] + bv;
    }
  }
}

// ---------------------------------------------------------------------------
// bf16 MFMA flash attention — R13-proven structure with the tile body
// specialized on diag: non-diagonal tiles (94%) get a branch-free body
// (nbmax/diag constant-folded via always-inlined lambda call sites).
// ---------------------------------------------------------------------------
constexpr int KVT = 64;

__global__ __launch_bounds__(256) void attn_mfma_kernel(
    const unsigned short* __restrict__ qkv,
    const unsigned short* __restrict__ Vg,   // [48][64][2048]
    unsigned short* __restrict__ y) {
  __shared__ unsigned short Ks[KVT * 64];    // 8KB, swizzled
  __shared__ unsigned short Vt[DD * 64];     // 8KB, swizzled
  __shared__ unsigned short Pl[4 * 16 * 64]; // 8KB, per-wave, swizzled

  const int tid = threadIdx.x;
  const int w = tid >> 6, l = tid & 63;
  const int lr = l & 15, lg = l >> 4;
  const int bh = blockIdx.x, b = bh / HH, h = bh % HH;
  const int g = 31 - blockIdx.y;           // longest-first
  const int qw = g * 64 + w * 16;

  const unsigned short* qbase = qkv + (size_t)b * TT * RS + h * DD;
  const unsigned short* kbase = qkv + (size_t)b * TT * RS + (HH + h) * DD;
  const unsigned short* vgb = Vg + (size_t)bh * DD * TT;

  const float qscale = 0.125f * 1.44269504f;
  const int e = lg ^ (lr & 7);
  const int e4 = e ^ 4;

  bf16x8 qf[2];
  {
    const unsigned short* qrow = qbase + (size_t)(qw + lr) * RS;
#pragma unroll
    for (int hf = 0; hf < 2; ++hf) {
      const u16x8 raw = *reinterpret_cast<const u16x8*>(qrow + lg * 8 + hf * 32);
      U8 t;
#pragma unroll
      for (int i = 0; i < 8; ++i) t.u[i] = f2bf(bf2f(raw[i]) * qscale);
      qf[hf] = t.v;
    }
  }

  f32x4 O[4];
  f32x4 ls = (f32x4)(0.f);
#pragma unroll
  for (int nb = 0; nb < 4; ++nb) O[nb] = (f32x4)(0.f);

  const int srow = tid >> 2, sc2 = (tid & 3) * 2;
  const int sw = srow & 7;
  const int sidx0 = srow * 64 + 8 * (sc2 ^ sw);
  const int sidx1 = srow * 64 + 8 * ((sc2 + 1) ^ sw);
  const int scol = (tid & 3) * 16;
  const unsigned short* kptr = kbase + (size_t)srow * RS + scol;
  const unsigned short* vptr = vgb + (size_t)srow * TT + scol;

  // tile body; call sites pass literal nbmax/diag so each specializes.
  auto tile_body = [&](const int kv0, const int nbmax, const bool diag) {
    f32x4 s[4];
#pragma unroll
    for (int nb = 0; nb < 4; ++nb) s[nb] = (f32x4)(0.f);
    __builtin_amdgcn_s_setprio(1);
#pragma unroll
    for (int nb = 0; nb < 4; ++nb) {
      if (nb >= nbmax) continue;
      const int krow = (nb * 16 + lr) * 64;
      const bf16x8 k0 = *reinterpret_cast<const bf16x8*>(&Ks[krow + 8 * e]);
      const bf16x8 k1 = *reinterpret_cast<const bf16x8*>(&Ks[krow + 8 * e4]);
      s[nb] = __builtin_amdgcn_mfma_f32_16x16x32_bf16(qf[0], k0, s[nb], 0, 0, 0);
      s[nb] = __builtin_amdgcn_mfma_f32_16x16x32_bf16(qf[1], k1, s[nb], 0, 0, 0);
    }
    __builtin_amdgcn_s_setprio(0);

    if (diag) {
      const int qrow = qw + lg * 4;
#pragma unroll
      for (int nb = 0; nb < 4; ++nb) {
        if (nb >= nbmax) continue;
        const int key = kv0 + nb * 16 + lr;
#pragma unroll
        for (int r = 0; r < 4; ++r)
          if (key > qrow + r) s[nb][r] = -1e30f;
      }
    }
#pragma unroll
    for (int r = 0; r < 4; ++r) {
      const int prow = lg * 4 + r;
      const int pswz = (prow & 7) << 3;
      unsigned short* pbase = &Pl[w * 1024 + prow * 64];
#pragma unroll
      for (int nb = 0; nb < 4; ++nb) {
        if (nb >= nbmax) {
          pbase[(nb * 16 + lr) ^ pswz] = 0;
          continue;
        }
        const float p = exp2f(s[nb][r]);
        ls[r] += p;
        BCV cv; cv.h = (__bf16)p;
        pbase[(nb * 16 + lr) ^ pswz] = cv.u;
      }
    }

    asm volatile("s_waitcnt lgkmcnt(0)" ::: "memory");

    {
      const unsigned short* pw = &Pl[w * 1024];
      const bf16x8 pa0 = *reinterpret_cast<const bf16x8*>(&pw[lr * 64 + 8 * e]);
      const bf16x8 pa1 = *reinterpret_cast<const bf16x8*>(&pw[lr * 64 + 8 * e4]);
      __builtin_amdgcn_s_setprio(1);
#pragma unroll
      for (int nb = 0; nb < 4; ++nb) {
        const int vrow = (nb * 16 + lr) * 64;
        const bf16x8 v0 = *reinterpret_cast<const bf16x8*>(&Vt[vrow + 8 * e]);
        const bf16x8 v1 = *reinterpret_cast<const bf16x8*>(&Vt[vrow + 8 * e4]);
        O[nb] = __builtin_amdgcn_mfma_f32_16x16x32_bf16(pa0, v0, O[nb], 0, 0, 0);
        O[nb] = __builtin_amdgcn_mfma_f32_16x16x32_bf16(pa1, v1, O[nb], 0, 0, 0);
      }
      __builtin_amdgcn_s_setprio(0);
    }
  };

  const int ntiles = g + 1;
  u16x8 kr0 = *reinterpret_cast<const u16x8*>(kptr);
  u16x8 kr1 = *reinterpret_cast<const u16x8*>(kptr + 8);
  u16x8 vr0 = *reinterpret_cast<const u16x8*>(vptr);
  u16x8 vr1 = *reinterpret_cast<const u16x8*>(vptr + 8);

  for (int t = 0; t < ntiles; ++t) {
    const int kv0 = t * KVT;
    __syncthreads();
    *reinterpret_cast<u16x8*>(&Ks[sidx0]) = kr0;
    *reinterpret_cast<u16x8*>(&Ks[sidx1]) = kr1;
    *reinterpret_cast<u16x8*>(&Vt[sidx0]) = vr0;
    *reinterpret_cast<u16x8*>(&Vt[sidx1]) = vr1;
    if (t + 1 < ntiles) {
      kptr += (size_t)KVT * RS;
      vptr += KVT;
      kr0 = *reinterpret_cast<const u16x8*>(kptr);
      kr1 = *reinterpret_cast<const u16x8*>(kptr + 8);
      vr0 = *reinterpret_cast<const u16x8*>(vptr);
      vr1 = *reinterpret_cast<const u16x8*>(vptr + 8);
    }
    __syncthreads();

    if (t == g) tile_body(kv0, w + 1, true);   // diagonal tile (branchy)
    else        tile_body(kv0, 4, false);      // interior tile (branch-free)
  }

#pragma unroll
  for (int off = 1; off < 16; off <<= 1)
#pragma unroll
    for (int r = 0; r < 4; ++r) ls[r] += __shfl_xor(ls[r], off, 64);
  f32x4 inv;
#pragma unroll
  for (int r = 0; r < 4; ++r) inv[r] = 1.f / ls[r];
#pragma unroll
  for (int nb = 0; nb < 4; ++nb)
#pragma unroll
    for (int r = 0; r < 4; ++r)
      y[((size_t)b * TT + qw + lg * 4 + r) * CC + h * DD + nb * 16 + lr] =
          f2bf(O[nb][r] * inv[r]);
}

extern "C" void kernel_launch(void* const* d_in, const int* in_sizes, int n_in,
                              void* d_out, int out_size, void* d_ws, size_t ws_size,
                              hipStream_t stream) {
  const float* x      = (const float*)d_in[0];
  const float* W_attn = (const float*)d_in[2];
  const float* b_attn = (const float*)d_in[3];
  const float* W_proj = (const float*)d_in[4];
  const float* b_proj = (const float*)d_in[5];
  float* out = (float*)d_out;

  const int M = BB * TT;  // 8192
  unsigned short* qkvb = (unsigned short*)d_ws;            // [8192][2304]
  unsigned short* xb   = qkvb + (size_t)M * RS;            // [8192][768]
  unsigned short* yb   = xb + (size_t)M * CC;              // [8192][768]
  unsigned short* Wt1  = yb + (size_t)M * CC;              // [2304][768]
  unsigned short* Wt2  = Wt1 + (size_t)RS * CC;            // [768][768]
  unsigned short* Vg   = Wt2 + (size_t)CC * CC;            // [48][64][2048]

  cvt_bf16_kernel<<<1024, 256, 0, stream>>>(x, xb, M * CC / 8);
  transpose2_kernel<<<dim3(RS / 64, CC / 64, 2), 256, 0, stream>>>(
      W_attn, Wt1, W_proj, Wt2);

  gemm1_kernel<<<dim3(RS / 128, M / 128), 256, 0, stream>>>(
      xb, Wt1, b_attn, qkvb, Vg, M, RS, CC);

  attn_mfma_kernel<<<dim3(BB * HH, 32), 256, 0, stream>>>(qkvb, Vg, yb);

  gemm2_kernel<<<dim3(CC / 128, M / 128), 256, 0, stream>>>(
      yb, Wt2, b_proj, out, M, CC, CC);
}